// Round 1
// baseline (779.373 us; speedup 1.0000x reference)
//
#include <hip/hip_runtime.h>
#include <cstddef>

// ---------------- problem constants (fixed by setup_inputs) ----------------
#define BB   8
#define CC   2
#define FF   256
#define TT   4160     // ncoefs
#define TPAD 4288     // TT + 2*HOP
#define SS   64       // nb_slices
#define NW   128      // NWIN
#define KW   256      // 2*NWIN
#define EPSV 1e-5f

// ---------------- ws layout (float offsets) ----------------
// y: [BB][CC][FF][SS][NW] fp32 = 33,554,432 floats (134.2 MB)
#define YS        33554432
#define WS_DSUM   (YS)          // [CC*SS] per-(c,s) sum
#define WS_DSQ    (YS + 128)    // [CC*SS] per-(c,s) sumsq
#define WS_DA     (YS + 256)    // [CC*SS] BN scale a
#define WS_DB     (YS + 384)    // [CC*SS] BN shift b
#define WS_DISUM  (YS + 512)    // [5*CC] per-(bucket,c) sum
#define WS_DISQ   (YS + 528)    // [5*CC] per-(bucket,c) sumsq

__global__ __launch_bounds__(256) void k_zero(float* __restrict__ p, int n) {
    int i = blockIdx.x * 256 + threadIdx.x;
    if (i < n) p[i] = 0.f;
}

// ---------------- stage 1: normalize + deoverlap GEMM + per-(c,s) stats ----------------
// grid: BB*CC*FF blocks (one per (b,c,f) row), 256 threads.
// y[r, s, n] = sum_w xs[s*64 + w] * W_deo[n, w],  xs = padded normalized x row.
__global__ __launch_bounds__(256) void k_deoverlap(
    const float* __restrict__ x, const float* __restrict__ imean,
    const float* __restrict__ iscale, const float* __restrict__ Wd,
    float* __restrict__ y, float* __restrict__ dsum, float* __restrict__ dsq)
{
    __shared__ float xs[TPAD];        // 17,152 B
    __shared__ float wt[32][132];     // 16,896 B (transposed W chunk, padded +4)
    const int r   = blockIdx.x;               // (b*CC + c)*FF + f
    const int f   = r & (FF - 1);
    const int c   = (r >> 8) & (CC - 1);
    const int tid = threadIdx.x;
    const float mval = imean[f], sval = iscale[f];
    const float* xr = x + (size_t)r * TT;

    for (int i = tid; i < TPAD; i += 256) {
        int t = i - 64;
        xs[i] = (t >= 0 && t < TT) ? (xr[t] + mval) * sval : 0.f;
    }

    const int ng = tid & 15, sg = tid >> 4;
    const int n0 = ng << 3, s0 = sg << 2;     // thread tile: 4 slices x 8 n
    float acc[4][8];
#pragma unroll
    for (int i = 0; i < 4; ++i)
#pragma unroll
        for (int j = 0; j < 8; ++j) acc[i][j] = 0.f;

    for (int k0 = 0; k0 < KW; k0 += 32) {
        __syncthreads();  // protect wt from previous chunk's readers (and xs on first iter)
#pragma unroll
        for (int ii = 0; ii < 16; ++ii) {     // 4096 elems / 256 threads
            int idx = tid + ii * 256;
            int n = idx >> 5, w = idx & 31;   // coalesced global read
            wt[w][n] = Wd[n * KW + k0 + w];
        }
        __syncthreads();
        const int xb = s0 * 64 + k0;
#pragma unroll 4
        for (int w = 0; w < 32; ++w) {
            const float4 wa = *(const float4*)&wt[w][n0];
            const float4 wb = *(const float4*)&wt[w][n0 + 4];
            const float wv[8] = {wa.x, wa.y, wa.z, wa.w, wb.x, wb.y, wb.z, wb.w};
            const float xv[4] = {xs[xb + w], xs[xb + w + 64],
                                 xs[xb + w + 128], xs[xb + w + 192]};
#pragma unroll
            for (int i = 0; i < 4; ++i)
#pragma unroll
                for (int j = 0; j < 8; ++j)
                    acc[i][j] = fmaf(xv[i], wv[j], acc[i][j]);
        }
    }

    float* yr = y + (size_t)r * (SS * NW);
#pragma unroll
    for (int i = 0; i < 4; ++i) {
        const int s = s0 + i;
        float4 v0 = make_float4(acc[i][0], acc[i][1], acc[i][2], acc[i][3]);
        float4 v1 = make_float4(acc[i][4], acc[i][5], acc[i][6], acc[i][7]);
        *(float4*)&yr[s * NW + n0]     = v0;
        *(float4*)&yr[s * NW + n0 + 4] = v1;
        float ps = 0.f, pq = 0.f;
#pragma unroll
        for (int j = 0; j < 8; ++j) { ps += acc[i][j]; pq += acc[i][j] * acc[i][j]; }
        // reduce over the 16 ng-lanes sharing (sg, i) — contiguous 16-lane groups
#pragma unroll
        for (int off = 8; off > 0; off >>= 1) {
            ps += __shfl_down(ps, off, 16);
            pq += __shfl_down(pq, off, 16);
        }
        if (ng == 0) {
            atomicAdd(&dsum[c * SS + s], ps);
            atomicAdd(&dsq[c * SS + s], pq);
        }
    }
}

// ---------------- stage 1b: finalize per-(c,s) BN coefficients ----------------
__global__ void k_deo_ab(const float* __restrict__ dsum, const float* __restrict__ dsq,
                         const float* __restrict__ g, const float* __restrict__ be,
                         float* __restrict__ da, float* __restrict__ db)
{
    int i = threadIdx.x;          // c*64 + s
    if (i < CC * SS) {
        int c = i >> 6;
        const float N = (float)(BB * FF * NW);   // 262144
        float mean = dsum[i] / N;
        float var  = dsq[i] / N - mean * mean;
        float a = g[c] * rsqrtf(var + EPSV);
        da[i] = a;
        db[i] = be[c] - mean * a;
    }
}

// ---------------- stage 2: BN+ReLU(y) then ragged deinterp GEMM + per-c stats ----------------
// grid: BB*CC*freqs blocks (one per (b,c,f) row within bucket), 256 threads.
template <int MT>
__global__ __launch_bounds__(256) void k_deinterp(
    const float* __restrict__ y, const float* __restrict__ Wdi,
    const float* __restrict__ da, const float* __restrict__ db,
    float* __restrict__ z, float* __restrict__ disum, float* __restrict__ disq,
    int p, int freqs, int statBase)
{
    constexpr int MTP   = MT + 4;
    constexpr int MTILE = (MT == 128) ? 8 : 4;
    constexpr int MG    = MT / MTILE;         // m-groups; threads used = MG*16
    __shared__ float ya[SS][132];             // 33,792 B, BN+ReLU applied
    __shared__ float wt[32][MTP];             // transposed W t-chunk

    const int r   = blockIdx.x;               // (b*CC + c)*freqs + fl
    const int fl  = r % freqs;
    const int c   = (r / freqs) & 1;
    const int b   = r / (freqs * CC);
    const int tid = threadIdx.x;
    const float* yr = y + ((size_t)((b * CC + c) * FF + p + fl)) * (SS * NW);

    for (int idx = tid; idx < SS * NW / 4; idx += 256) {
        int s  = idx >> 5;
        int n4 = (idx & 31) << 2;
        float a = da[c * SS + s], bb = db[c * SS + s];
        float4 v = *(const float4*)&yr[s * NW + n4];
        v.x = fmaxf(fmaf(v.x, a, bb), 0.f);
        v.y = fmaxf(fmaf(v.y, a, bb), 0.f);
        v.z = fmaxf(fmaf(v.z, a, bb), 0.f);
        v.w = fmaxf(fmaf(v.w, a, bb), 0.f);
        *(float4*)&ya[s][n4] = v;
    }

    const int mg = tid % MG, sg = tid / MG;
    const int m0 = mg * MTILE, s0 = sg << 2;  // thread tile: 4 slices x MTILE m
    float acc[4][MTILE];
#pragma unroll
    for (int i = 0; i < 4; ++i)
#pragma unroll
        for (int j = 0; j < MTILE; ++j) acc[i][j] = 0.f;

    for (int ct = 0; ct < 4; ++ct) {          // K=128 in 4 chunks of 32
        __syncthreads();
        for (int idx = tid; idx < MT * 32; idx += 256) {
            int m = idx >> 5, tt = idx & 31;  // coalesced global read
            wt[tt][m] = Wdi[m * NW + ct * 32 + tt];
        }
        __syncthreads();
        if (tid < MG * 16) {
            const int tb = ct * 32;
#pragma unroll 4
            for (int tt = 0; tt < 32; ++tt) {
                float xv[4];
#pragma unroll
                for (int i = 0; i < 4; ++i) xv[i] = ya[s0 + i][tb + tt];
#pragma unroll
                for (int j4 = 0; j4 < MTILE; j4 += 4) {
                    float4 wv = *(const float4*)&wt[tt][m0 + j4];
#pragma unroll
                    for (int i = 0; i < 4; ++i) {
                        acc[i][j4 + 0] = fmaf(xv[i], wv.x, acc[i][j4 + 0]);
                        acc[i][j4 + 1] = fmaf(xv[i], wv.y, acc[i][j4 + 1]);
                        acc[i][j4 + 2] = fmaf(xv[i], wv.z, acc[i][j4 + 2]);
                        acc[i][j4 + 3] = fmaf(xv[i], wv.w, acc[i][j4 + 3]);
                    }
                }
            }
        }
    }

    float lsum = 0.f, lsq = 0.f;
    if (tid < MG * 16) {
        float* zr = z + (size_t)r * (SS * MT);
#pragma unroll
        for (int i = 0; i < 4; ++i) {
            int s = s0 + i;
#pragma unroll
            for (int j4 = 0; j4 < MTILE; j4 += 4) {
                float4 v = make_float4(acc[i][j4], acc[i][j4 + 1],
                                       acc[i][j4 + 2], acc[i][j4 + 3]);
                *(float4*)&zr[s * MT + m0 + j4] = v;
                lsum += v.x + v.y + v.z + v.w;
                lsq  += v.x * v.x + v.y * v.y + v.z * v.z + v.w * v.w;
            }
        }
    }
#pragma unroll
    for (int off = 32; off > 0; off >>= 1) {
        lsum += __shfl_down(lsum, off, 64);
        lsq  += __shfl_down(lsq, off, 64);
    }
    if ((tid & 63) == 0) {
        atomicAdd(&disum[statBase + c], lsum);
        atomicAdd(&disq[statBase + c], lsq);
    }
}

// ---------------- stage 2b: per-channel BN+ReLU applied in place on d_out ----------------
__global__ __launch_bounds__(256) void k_bn_out(
    float* __restrict__ z, const float* __restrict__ g, const float* __restrict__ be,
    const float* __restrict__ dsum, const float* __restrict__ dsq,
    float invN, int cstride4, int size4)
{
    int i4 = blockIdx.x * 256 + threadIdx.x;
    if (i4 >= size4) return;
    int c = (i4 / cstride4) & 1;
    float mean = dsum[c] * invN;
    float var  = dsq[c] * invN - mean * mean;
    float a  = g[c] * rsqrtf(var + EPSV);
    float bb = be[c] - mean * a;
    float4 v = ((const float4*)z)[i4];
    v.x = fmaxf(fmaf(v.x, a, bb), 0.f);
    v.y = fmaxf(fmaf(v.y, a, bb), 0.f);
    v.z = fmaxf(fmaf(v.z, a, bb), 0.f);
    v.w = fmaxf(fmaf(v.w, a, bb), 0.f);
    ((float4*)z)[i4] = v;
}

// ---------------- launch ----------------
extern "C" void kernel_launch(void* const* d_in, const int* in_sizes, int n_in,
                              void* d_out, int out_size, void* d_ws, size_t ws_size,
                              hipStream_t stream)
{
    const float* x      = (const float*)d_in[0];
    const float* imean  = (const float*)d_in[1];
    const float* iscale = (const float*)d_in[2];
    const float* Wdeo   = (const float*)d_in[3];
    const float* gdeo   = (const float*)d_in[4];
    const float* bdeo   = (const float*)d_in[5];
    // dict order: W_di{i}, g_di{i}, b_di{i} interleaved starting at index 7
    const float* Wdi[5] = {(const float*)d_in[7],  (const float*)d_in[10],
                           (const float*)d_in[13], (const float*)d_in[16],
                           (const float*)d_in[19]};
    const float* gdi[5] = {(const float*)d_in[8],  (const float*)d_in[11],
                           (const float*)d_in[14], (const float*)d_in[17],
                           (const float*)d_in[20]};
    const float* bdi[5] = {(const float*)d_in[9],  (const float*)d_in[12],
                           (const float*)d_in[15], (const float*)d_in[18],
                           (const float*)d_in[21]};
    float* out = (float*)d_out;
    float* ws  = (float*)d_ws;

    float* y     = ws;
    float* dsum  = ws + WS_DSUM;
    float* dsq   = ws + WS_DSQ;
    float* da    = ws + WS_DA;
    float* db    = ws + WS_DB;
    float* disum = ws + WS_DISUM;
    float* disq  = ws + WS_DISQ;

    k_zero<<<4, 256, 0, stream>>>(ws + YS, 1024);

    k_deoverlap<<<BB * CC * FF, 256, 0, stream>>>(x, imean, iscale, Wdeo, y, dsum, dsq);
    k_deo_ab<<<1, 128, 0, stream>>>(dsum, dsq, gdeo, bdeo, da, db);

    // bucket tables: freqs {32,32,64,64,64}, MT {16,32,48,64,128}
    static const int offs[5]   = {0, 524288, 1572864, 4718592, 8912896};
    static const int sizes[5]  = {524288, 1048576, 3145728, 4194304, 8388608};
    static const int freqsA[5] = {32, 32, 64, 64, 64};
    static const int mtsA[5]   = {16, 32, 48, 64, 128};

    k_deinterp<16> <<<BB * CC * 32, 256, 0, stream>>>(y, Wdi[0], da, db, out + offs[0], disum, disq,   0, 32, 0);
    k_deinterp<32> <<<BB * CC * 32, 256, 0, stream>>>(y, Wdi[1], da, db, out + offs[1], disum, disq,  32, 32, 2);
    k_deinterp<48> <<<BB * CC * 64, 256, 0, stream>>>(y, Wdi[2], da, db, out + offs[2], disum, disq,  64, 64, 4);
    k_deinterp<64> <<<BB * CC * 64, 256, 0, stream>>>(y, Wdi[3], da, db, out + offs[3], disum, disq, 128, 64, 6);
    k_deinterp<128><<<BB * CC * 64, 256, 0, stream>>>(y, Wdi[4], da, db, out + offs[4], disum, disq, 192, 64, 8);

    for (int k = 0; k < 5; ++k) {
        int size4    = sizes[k] / 4;
        int cstride4 = freqsA[k] * SS * mtsA[k] / 4;
        float invN   = 1.f / (float)(sizes[k] / 2);
        int grid     = (size4 + 255) / 256;
        k_bn_out<<<grid, 256, 0, stream>>>(out + offs[k], gdi[k], bdi[k],
                                           disum + 2 * k, disq + 2 * k,
                                           invN, cstride4, size4);
    }
}

// Round 5
// 662.999 us; speedup vs baseline: 1.1755x; 1.1755x over previous
//
#include <hip/hip_runtime.h>
#include <cstddef>

// ---------------- problem constants ----------------
#define BB   8
#define CC   2
#define FF   256
#define TT   4160      // ncoefs
#define SS   64        // nb_slices
#define NW   128       // NWIN
#define KW   256       // 2*NWIN
#define EPSV 1e-5f

typedef __attribute__((ext_vector_type(8))) short bf16x8;   // 8 bf16 = 4 VGPRs
typedef __attribute__((ext_vector_type(4))) float f32x4;

// ---------------- ws layout (float offsets) ----------------
// y  : bf16 [4096][64][128] = 33,554,432 ushort = 16,777,216 floats
// z  : bf16 concat buckets  = 17,301,504 ushort =  8,650,752 floats
// w1 : bf16 frag-ordered W_deo = 32,768 ushort  =     16,384 floats
// stats: 1024 floats.  Total ≈ 101.8 MB.
#define YOFF   0
#define ZOFF   16777216
#define W1OFF  25427968
#define STATF  25444352
#define OFF_DSUM  0
#define OFF_DSQ   128
#define OFF_DA    256
#define OFF_DB    384
#define OFF_DISUM 512
#define OFF_DISQ  528
#define OFF_DIAB  544

// manual bf16 conversions (RNE)
__device__ __forceinline__ unsigned short f2bf(float f) {
    unsigned int u = __builtin_bit_cast(unsigned int, f);
    u = (u + 0x7FFFu + ((u >> 16) & 1u)) >> 16;
    return (unsigned short)u;
}
__device__ __forceinline__ float bf2f(unsigned short h) {
    return __builtin_bit_cast(float, (unsigned int)h << 16);
}

// ---------------- prep: zero stats + convert W_deo to frag-ordered bf16 ----------------
__global__ __launch_bounds__(256) void k_prep(
    const float* __restrict__ Wdeo, unsigned short* __restrict__ w1,
    float* __restrict__ statz)
{
    int gid = blockIdx.x * 256 + threadIdx.x;
    if (gid < 1024) statz[gid] = 0.f;
    int id = gid - 1024;
    if (id >= 0 && id < 32768) {
        int j = id & 7, lane = (id >> 3) & 63, nt = (id >> 9) & 7, ks = id >> 12;
        int n = nt * 16 + (lane & 15);
        int k = ks * 32 + ((lane >> 4) << 3) + j;
        w1[id] = f2bf(Wdeo[n * KW + k]);
    }
}

// ---------------- stage 1: normalize + deoverlap MFMA + per-(c,s) stats ----------------
__global__ __launch_bounds__(256) void k_deoverlap(
    const float* __restrict__ x, const float* __restrict__ imean,
    const float* __restrict__ iscale, const unsigned short* __restrict__ w1,
    unsigned short* __restrict__ y, float* __restrict__ dsum, float* __restrict__ dsq)
{
    __shared__ __align__(16) unsigned short xs[2][4288];
    const int tid = threadIdx.x;
    const int r0  = blockIdx.x * 2;
    const int c   = (r0 >> 8) & 1;

    for (int row = 0; row < 2; ++row) {
        const int r = r0 + row;
        const float mval = imean[r & 255], sval = iscale[r & 255];
        const float* xr = x + (size_t)r * TT;
        for (int p2 = tid; p2 < 2144; p2 += 256) {
            int i = p2 * 2;
            int t = i - 64;
            float v0 = 0.f, v1 = 0.f;
            if (t >= 0 && t + 1 < TT) {
                float2 xv = *(const float2*)&xr[t];
                v0 = (xv.x + mval) * sval;
                v1 = (xv.y + mval) * sval;
            }
            int phys = i ^ (((i >> 6) & 7) << 3);
            unsigned int pk = (unsigned int)f2bf(v0) | ((unsigned int)f2bf(v1) << 16);
            *(unsigned int*)&xs[row][phys] = pk;
        }
    }
    __syncthreads();

    const int lane = tid & 63, wv = tid >> 6;
    const int q = lane >> 4, m = lane & 15;

    f32x4 acc[2][4][2] = {};
    for (int ks = 0; ks < 8; ++ks) {
        const int k0 = ks * 32;
        bf16x8 B0 = *(const bf16x8*)(w1 + ((size_t)((ks * 8 + 2 * wv + 0) * 64 + lane) << 3));
        bf16x8 B1 = *(const bf16x8*)(w1 + ((size_t)((ks * 8 + 2 * wv + 1) * 64 + lane) << 3));
#pragma unroll
        for (int row = 0; row < 2; ++row)
#pragma unroll
            for (int st = 0; st < 4; ++st) {
                int idx  = (st * 16 + m) * 64 + k0 + q * 8;
                int phys = idx ^ (((idx >> 6) & 7) << 3);
                bf16x8 A = *(const bf16x8*)&xs[row][phys];
                acc[row][st][0] = __builtin_amdgcn_mfma_f32_16x16x32_bf16(A, B0, acc[row][st][0], 0, 0, 0);
                acc[row][st][1] = __builtin_amdgcn_mfma_f32_16x16x32_bf16(A, B1, acc[row][st][1], 0, 0, 0);
            }
    }

#pragma unroll
    for (int row = 0; row < 2; ++row)
#pragma unroll
        for (int st = 0; st < 4; ++st)
#pragma unroll
            for (int t = 0; t < 2; ++t) {
                int n = (2 * wv + t) * 16 + m;
#pragma unroll
                for (int reg = 0; reg < 4; ++reg) {
                    int s = st * 16 + q * 4 + reg;
                    y[((size_t)(r0 + row) * SS + s) * NW + n] = f2bf(acc[row][st][t][reg]);
                }
            }

#pragma unroll
    for (int st = 0; st < 4; ++st)
#pragma unroll
        for (int reg = 0; reg < 4; ++reg) {
            float ps = 0.f, pq = 0.f;
#pragma unroll
            for (int row = 0; row < 2; ++row)
#pragma unroll
                for (int t = 0; t < 2; ++t) {
                    float v = acc[row][st][t][reg];
                    ps += v; pq += v * v;
                }
#pragma unroll
            for (int off = 8; off > 0; off >>= 1) {
                ps += __shfl_down(ps, off, 16);
                pq += __shfl_down(pq, off, 16);
            }
            if (m == 0) {
                int s = st * 16 + q * 4 + reg;
                atomicAdd(&dsum[c * SS + s], ps);
                atomicAdd(&dsq[c * SS + s], pq);
            }
        }
}

// ---------------- stage 1b ----------------
__global__ void k_deo_ab(const float* __restrict__ dsum, const float* __restrict__ dsq,
                         const float* __restrict__ g, const float* __restrict__ be,
                         float* __restrict__ da, float* __restrict__ db)
{
    int i = threadIdx.x;
    if (i < CC * SS) {
        int c = i >> 6;
        const float N = (float)(BB * FF * NW);
        float mean = dsum[i] / N;
        float var  = dsq[i] / N - mean * mean;
        float a = g[c] * rsqrtf(var + EPSV);
        da[i] = a;
        db[i] = be[c] - mean * a;
    }
}

// ---------------- stage 2 UNIFIED (NT structurally = 1 per block) ----------------
__global__ __launch_bounds__(256) void k_deinterp_u(
    const unsigned short* __restrict__ y,
    const float* __restrict__ W0, const float* __restrict__ W1,
    const float* __restrict__ W2, const float* __restrict__ W3,
    const float* __restrict__ W4,
    const float* __restrict__ da, const float* __restrict__ db,
    unsigned short* __restrict__ z)
{
    const int cum[6]    = {0, 128, 384, 1152, 2176, 4224};
    const int pA[5]     = {0, 32, 64, 128, 192};
    const int freqsA[5] = {32, 32, 64, 64, 64};
    const int mtA[5]    = {16, 32, 48, 64, 128};
    const int lgFG[5]   = {3, 3, 4, 4, 4};
    const size_t zoffA[5] = {0, 524288, 1572864, 4718592, 8912896};

    int bid = blockIdx.x;
    int k = 0;
    while (k < 4 && bid >= cum[k + 1]) ++k;
    int r = bid - cum[k];
    const int bc = r & 15;  r >>= 4;
    const int fg = r & ((1 << lgFG[k]) - 1);
    const int mt = r >> lgFG[k];

    const float* W = (k == 0) ? W0 : (k == 1) ? W1 : (k == 2) ? W2 : (k == 3) ? W3 : W4;
    const int p = pA[k], freqs = freqsA[k], MT = mtA[k];
    unsigned short* zz = z + zoffA[k];

    const int tid = threadIdx.x, lane = tid & 63, wv = tid >> 6;
    const int q = lane >> 4, m = lane & 15;
    const int c = bc & 1;
    const int s = wv * 16 + m;
    const float aS = da[c * SS + s], bS = db[c * SS + s];

    f32x4 acc[4] = {};
    const unsigned short* ybase = y + ((size_t)(bc * FF + p + fg * 4) * SS) * NW;
    const float* wrow = W + (size_t)(mt * 16 + m) * NW;

    for (int ks = 0; ks < 4; ++ks) {
        const float* wp = wrow + ks * 32 + q * 8;
        float4 wa = *(const float4*)wp;
        float4 wb = *(const float4*)(wp + 4);
        bf16x8 B;
        B[0] = (short)f2bf(wa.x); B[1] = (short)f2bf(wa.y);
        B[2] = (short)f2bf(wa.z); B[3] = (short)f2bf(wa.w);
        B[4] = (short)f2bf(wb.x); B[5] = (short)f2bf(wb.y);
        B[6] = (short)f2bf(wb.z); B[7] = (short)f2bf(wb.w);
#pragma unroll
        for (int g = 0; g < 4; ++g) {
            const unsigned short* yp = ybase + ((size_t)g * SS + s) * NW + ks * 32 + q * 8;
            bf16x8 ar = *(const bf16x8*)yp;
            bf16x8 af;
#pragma unroll
            for (int j = 0; j < 8; ++j) {
                float f = bf2f((unsigned short)ar[j]);
                f = fmaxf(fmaf(f, aS, bS), 0.f);
                af[j] = (short)f2bf(f);
            }
            acc[g] = __builtin_amdgcn_mfma_f32_16x16x32_bf16(af, B, acc[g], 0, 0, 0);
        }
    }

#pragma unroll
    for (int g = 0; g < 4; ++g) {
        size_t zrow = (size_t)(bc * freqs + fg * 4 + g) * SS;
#pragma unroll
        for (int reg = 0; reg < 4; ++reg) {
            int srow = wv * 16 + q * 4 + reg;
            zz[(zrow + srow) * MT + mt * 16 + m] = f2bf(acc[g][reg]);
        }
    }
}

// ---------------- stage 2 stats from stored z ----------------
__global__ __launch_bounds__(256) void k_zstat(const unsigned short* __restrict__ z,
                                               float* __restrict__ disum,
                                               float* __restrict__ disq)
{
    __shared__ float ssum[4], ssq[4];
    const int tid = threadIdx.x, lane = tid & 63, wv = tid >> 6;
    size_t e0 = (size_t)blockIdx.x * 8192;
    int kb; size_t off, cs;
    if (e0 < 524288)       { kb = 0; off = 0;       cs = 32768;  }
    else if (e0 < 1572864) { kb = 1; off = 524288;  cs = 65536;  }
    else if (e0 < 4718592) { kb = 2; off = 1572864; cs = 196608; }
    else if (e0 < 8912896) { kb = 3; off = 4718592; cs = 262144; }
    else                   { kb = 4; off = 8912896; cs = 524288; }
    int c = (int)(((e0 - off) / cs) & 1);

    float s = 0.f, q = 0.f;
#pragma unroll
    for (int it = 0; it < 4; ++it) {
        const unsigned short* pz = z + e0 + ((size_t)(it * 256 + tid) << 3);
        ushort4 u0 = *(const ushort4*)pz;
        ushort4 u1 = *(const ushort4*)(pz + 4);
        float v;
        v = bf2f(u0.x); s += v; q += v * v;
        v = bf2f(u0.y); s += v; q += v * v;
        v = bf2f(u0.z); s += v; q += v * v;
        v = bf2f(u0.w); s += v; q += v * v;
        v = bf2f(u1.x); s += v; q += v * v;
        v = bf2f(u1.y); s += v; q += v * v;
        v = bf2f(u1.z); s += v; q += v * v;
        v = bf2f(u1.w); s += v; q += v * v;
    }
#pragma unroll
    for (int o = 32; o > 0; o >>= 1) {
        s += __shfl_down(s, o, 64);
        q += __shfl_down(q, o, 64);
    }
    if (lane == 0) { ssum[wv] = s; ssq[wv] = q; }
    __syncthreads();
    if (tid == 0) {
        atomicAdd(&disum[kb * 2 + c], ssum[0] + ssum[1] + ssum[2] + ssum[3]);
        atomicAdd(&disq[kb * 2 + c],  ssq[0] + ssq[1] + ssq[2] + ssq[3]);
    }
}

// ---------------- stage 2b ----------------
__global__ void k_di_ab(const float* __restrict__ disum, const float* __restrict__ disq,
                        const float* __restrict__ g0, const float* __restrict__ g1,
                        const float* __restrict__ g2, const float* __restrict__ g3,
                        const float* __restrict__ g4,
                        const float* __restrict__ b0, const float* __restrict__ b1,
                        const float* __restrict__ b2, const float* __restrict__ b3,
                        const float* __restrict__ b4,
                        float* __restrict__ ab)
{
    int i = threadIdx.x;
    if (i < 10) {
        int kb = i >> 1, c = i & 1;
        const float Nv[5] = {262144.f, 524288.f, 1572864.f, 2097152.f, 4194304.f};
        const float* gp[5] = {g0, g1, g2, g3, g4};
        const float* bp[5] = {b0, b1, b2, b3, b4};
        float mean = disum[i] / Nv[kb];
        float var  = disq[i] / Nv[kb] - mean * mean;
        float a = gp[kb][c] * rsqrtf(var + EPSV);
        ab[i * 2]     = a;
        ab[i * 2 + 1] = bp[kb][c] - mean * a;
    }
}

// ---------------- BN+ReLU epilogue: bf16 z -> fp32 out ----------------
__global__ __launch_bounds__(256) void k_bn_out(
    const unsigned short* __restrict__ z, const float* __restrict__ ab,
    float* __restrict__ out)
{
    int i4 = blockIdx.x * 256 + threadIdx.x;
    if (i4 >= 4325376) return;
    int kb, off4, cs4;
    if (i4 < 131072)       { kb = 0; off4 = 0;       cs4 = 8192;   }
    else if (i4 < 393216)  { kb = 1; off4 = 131072;  cs4 = 16384;  }
    else if (i4 < 1179648) { kb = 2; off4 = 393216;  cs4 = 49152;  }
    else if (i4 < 2228224) { kb = 3; off4 = 1179648; cs4 = 65536;  }
    else                   { kb = 4; off4 = 2228224; cs4 = 131072; }
    int c = ((i4 - off4) / cs4) & 1;
    float a = ab[(kb * 2 + c) * 2], b = ab[(kb * 2 + c) * 2 + 1];
    ushort4 u = *(const ushort4*)(z + (size_t)i4 * 4);
    float4 o;
    o.x = fmaxf(fmaf(bf2f(u.x), a, b), 0.f);
    o.y = fmaxf(fmaf(bf2f(u.y), a, b), 0.f);
    o.z = fmaxf(fmaf(bf2f(u.z), a, b), 0.f);
    o.w = fmaxf(fmaf(bf2f(u.w), a, b), 0.f);
    *(float4*)(out + (size_t)i4 * 4) = o;
}

// ---------------- launch ----------------
extern "C" void kernel_launch(void* const* d_in, const int* in_sizes, int n_in,
                              void* d_out, int out_size, void* d_ws, size_t ws_size,
                              hipStream_t stream)
{
    const float* x      = (const float*)d_in[0];
    const float* imean  = (const float*)d_in[1];
    const float* iscale = (const float*)d_in[2];
    const float* Wdeo   = (const float*)d_in[3];
    const float* gdeo   = (const float*)d_in[4];
    const float* bdeo   = (const float*)d_in[5];
    const float* Wdi[5] = {(const float*)d_in[7],  (const float*)d_in[10],
                           (const float*)d_in[13], (const float*)d_in[16],
                           (const float*)d_in[19]};
    const float* gdi[5] = {(const float*)d_in[8],  (const float*)d_in[11],
                           (const float*)d_in[14], (const float*)d_in[17],
                           (const float*)d_in[20]};
    const float* bdi[5] = {(const float*)d_in[9],  (const float*)d_in[12],
                           (const float*)d_in[15], (const float*)d_in[18],
                           (const float*)d_in[21]};
    float* out = (float*)d_out;
    float* ws  = (float*)d_ws;

    unsigned short* y  = (unsigned short*)(ws + YOFF);
    unsigned short* z  = (unsigned short*)(ws + ZOFF);
    unsigned short* w1 = (unsigned short*)(ws + W1OFF);
    float* st    = ws + STATF;
    float* dsum  = st + OFF_DSUM;
    float* dsq   = st + OFF_DSQ;
    float* da    = st + OFF_DA;
    float* db    = st + OFF_DB;
    float* disum = st + OFF_DISUM;
    float* disq  = st + OFF_DISQ;
    float* diab  = st + OFF_DIAB;

    k_prep<<<132, 256, 0, stream>>>(Wdeo, w1, st);

    k_deoverlap<<<BB * CC * FF / 2, 256, 0, stream>>>(x, imean, iscale, w1, y, dsum, dsq);
    k_deo_ab<<<1, 128, 0, stream>>>(dsum, dsq, gdeo, bdeo, da, db);

    k_deinterp_u<<<4224, 256, 0, stream>>>(y, Wdi[0], Wdi[1], Wdi[2], Wdi[3], Wdi[4],
                                           da, db, z);

    k_zstat<<<2112, 256, 0, stream>>>(z, disum, disq);

    k_di_ab<<<1, 16, 0, stream>>>(disum, disq,
                                  gdi[0], gdi[1], gdi[2], gdi[3], gdi[4],
                                  bdi[0], bdi[1], bdi[2], bdi[3], bdi[4], diab);

    k_bn_out<<<16896, 256, 0, stream>>>(z, diab, out);
}

// Round 6
// 311.888 us; speedup vs baseline: 2.4989x; 2.1258x over previous
//
#include <hip/hip_runtime.h>
#include <cstddef>

// ---------------- problem constants ----------------
#define BB   8
#define CC   2
#define FF   256
#define TT   4160      // ncoefs
#define SS   64        // nb_slices
#define NW   128       // NWIN
#define KW   256       // 2*NWIN
#define EPSV 1e-5f

typedef __attribute__((ext_vector_type(8))) short bf16x8;   // 8 bf16 = 4 VGPRs
typedef __attribute__((ext_vector_type(4))) float f32x4;

// ---------------- ws layout (float offsets) ----------------
// y  : bf16 [4096][64][128] = 33,554,432 ushort = 16,777,216 floats
// z  : bf16 concat buckets  = 17,301,504 ushort =  8,650,752 floats
// w1 : bf16 frag-ordered W_deo = 32,768 ushort  =     16,384 floats
// stats: 1024 + 64*256 replicas = 17,408 floats. Total ≈ 101.9 MB.
#define YOFF   0
#define ZOFF   16777216
#define W1OFF  25427968
#define STATF  25444352
#define OFF_DA    256
#define OFF_DB    384
#define OFF_DISUM 512
#define OFF_DISQ  528
#define OFF_DIAB  544
#define OFF_STATR 1024     // 64 replicas x [sum(128) | sq(128)]

// manual bf16 conversions (RNE)
__device__ __forceinline__ unsigned short f2bf(float f) {
    unsigned int u = __builtin_bit_cast(unsigned int, f);
    u = (u + 0x7FFFu + ((u >> 16) & 1u)) >> 16;
    return (unsigned short)u;
}
__device__ __forceinline__ float bf2f(unsigned short h) {
    return __builtin_bit_cast(float, (unsigned int)h << 16);
}

// ---------------- prep: zero stats(+replicas) + convert W_deo to frag-ordered bf16 ----------------
__global__ __launch_bounds__(256) void k_prep(
    const float* __restrict__ Wdeo, unsigned short* __restrict__ w1,
    float* __restrict__ statz)
{
    int gid = blockIdx.x * 256 + threadIdx.x;
    if (gid < 17408) statz[gid] = 0.f;
    int id = gid - 17408;
    if (id >= 0 && id < 32768) {
        int j = id & 7, lane = (id >> 3) & 63, nt = (id >> 9) & 7, ks = id >> 12;
        int n = nt * 16 + (lane & 15);
        int k = ks * 32 + ((lane >> 4) << 3) + j;
        w1[id] = f2bf(Wdeo[n * KW + k]);
    }
}

// ---------------- stage 1: normalize + deoverlap MFMA + per-(c,s) stats ----------------
// stats: shfl-reduce -> LDS combine across 4 waves -> 128 atomics/block into
// replica (blockIdx & 63) — kills the cross-XCD same-line atomic serialization.
__global__ __launch_bounds__(256) void k_deoverlap(
    const float* __restrict__ x, const float* __restrict__ imean,
    const float* __restrict__ iscale, const unsigned short* __restrict__ w1,
    unsigned short* __restrict__ y, float* __restrict__ statR)
{
    __shared__ __align__(16) unsigned short xs[2][4288];
    __shared__ float psA[4][64], pqA[4][64];
    const int tid = threadIdx.x;
    const int r0  = blockIdx.x * 2;
    const int c   = (r0 >> 8) & 1;

    for (int row = 0; row < 2; ++row) {
        const int r = r0 + row;
        const float mval = imean[r & 255], sval = iscale[r & 255];
        const float* xr = x + (size_t)r * TT;
        for (int p2 = tid; p2 < 2144; p2 += 256) {
            int i = p2 * 2;
            int t = i - 64;
            float v0 = 0.f, v1 = 0.f;
            if (t >= 0 && t + 1 < TT) {
                float2 xv = *(const float2*)&xr[t];
                v0 = (xv.x + mval) * sval;
                v1 = (xv.y + mval) * sval;
            }
            int phys = i ^ (((i >> 6) & 7) << 3);
            unsigned int pk = (unsigned int)f2bf(v0) | ((unsigned int)f2bf(v1) << 16);
            *(unsigned int*)&xs[row][phys] = pk;
        }
    }
    __syncthreads();

    const int lane = tid & 63, wv = tid >> 6;
    const int q = lane >> 4, m = lane & 15;

    f32x4 acc[2][4][2] = {};
    for (int ks = 0; ks < 8; ++ks) {
        const int k0 = ks * 32;
        bf16x8 B0 = *(const bf16x8*)(w1 + ((size_t)((ks * 8 + 2 * wv + 0) * 64 + lane) << 3));
        bf16x8 B1 = *(const bf16x8*)(w1 + ((size_t)((ks * 8 + 2 * wv + 1) * 64 + lane) << 3));
#pragma unroll
        for (int row = 0; row < 2; ++row)
#pragma unroll
            for (int st = 0; st < 4; ++st) {
                int idx  = (st * 16 + m) * 64 + k0 + q * 8;
                int phys = idx ^ (((idx >> 6) & 7) << 3);
                bf16x8 A = *(const bf16x8*)&xs[row][phys];
                acc[row][st][0] = __builtin_amdgcn_mfma_f32_16x16x32_bf16(A, B0, acc[row][st][0], 0, 0, 0);
                acc[row][st][1] = __builtin_amdgcn_mfma_f32_16x16x32_bf16(A, B1, acc[row][st][1], 0, 0, 0);
            }
    }

#pragma unroll
    for (int row = 0; row < 2; ++row)
#pragma unroll
        for (int st = 0; st < 4; ++st)
#pragma unroll
            for (int t = 0; t < 2; ++t) {
                int n = (2 * wv + t) * 16 + m;
#pragma unroll
                for (int reg = 0; reg < 4; ++reg) {
                    int s = st * 16 + q * 4 + reg;
                    y[((size_t)(r0 + row) * SS + s) * NW + n] = f2bf(acc[row][st][t][reg]);
                }
            }

#pragma unroll
    for (int st = 0; st < 4; ++st)
#pragma unroll
        for (int reg = 0; reg < 4; ++reg) {
            float ps = 0.f, pq = 0.f;
#pragma unroll
            for (int row = 0; row < 2; ++row)
#pragma unroll
                for (int t = 0; t < 2; ++t) {
                    float v = acc[row][st][t][reg];
                    ps += v; pq += v * v;
                }
#pragma unroll
            for (int off = 8; off > 0; off >>= 1) {
                ps += __shfl_down(ps, off, 16);
                pq += __shfl_down(pq, off, 16);
            }
            if (m == 0) {
                int s = st * 16 + q * 4 + reg;   // each wave covers s=0..63 once
                psA[wv][s] = ps;
                pqA[wv][s] = pq;
            }
        }
    __syncthreads();
    if (tid < 128) {
        int s = tid & 63, which = tid >> 6;
        float v = which ? (pqA[0][s] + pqA[1][s] + pqA[2][s] + pqA[3][s])
                        : (psA[0][s] + psA[1][s] + psA[2][s] + psA[3][s]);
        int rep = blockIdx.x & 63;
        atomicAdd(&statR[rep * 256 + which * 128 + c * SS + s], v);
    }
}

// ---------------- stage 1b: fold replicas -> per-(c,s) BN coefficients ----------------
__global__ void k_deo_ab(const float* __restrict__ statR,
                         const float* __restrict__ g, const float* __restrict__ be,
                         float* __restrict__ da, float* __restrict__ db)
{
    int i = threadIdx.x;          // 128 = c*64+s
    if (i < CC * SS) {
        float sm = 0.f, sq = 0.f;
        for (int rep = 0; rep < 64; ++rep) {
            sm += statR[rep * 256 + i];
            sq += statR[rep * 256 + 128 + i];
        }
        int c = i >> 6;
        const float N = (float)(BB * FF * NW);
        float mean = sm / N;
        float var  = sq / N - mean * mean;
        float a = g[c] * rsqrtf(var + EPSV);
        da[i] = a;
        db[i] = be[c] - mean * a;
    }
}

// ---------------- stage 2 UNIFIED (NT structurally = 1 per block) ----------------
__global__ __launch_bounds__(256) void k_deinterp_u(
    const unsigned short* __restrict__ y,
    const float* __restrict__ W0, const float* __restrict__ W1,
    const float* __restrict__ W2, const float* __restrict__ W3,
    const float* __restrict__ W4,
    const float* __restrict__ da, const float* __restrict__ db,
    unsigned short* __restrict__ z)
{
    const int cum[6]    = {0, 128, 384, 1152, 2176, 4224};
    const int pA[5]     = {0, 32, 64, 128, 192};
    const int freqsA[5] = {32, 32, 64, 64, 64};
    const int mtA[5]    = {16, 32, 48, 64, 128};
    const int lgFG[5]   = {3, 3, 4, 4, 4};
    const size_t zoffA[5] = {0, 524288, 1572864, 4718592, 8912896};

    int bid = blockIdx.x;
    int k = 0;
    while (k < 4 && bid >= cum[k + 1]) ++k;
    int r = bid - cum[k];
    const int bc = r & 15;  r >>= 4;
    const int fg = r & ((1 << lgFG[k]) - 1);
    const int mt = r >> lgFG[k];

    const float* W = (k == 0) ? W0 : (k == 1) ? W1 : (k == 2) ? W2 : (k == 3) ? W3 : W4;
    const int p = pA[k], freqs = freqsA[k], MT = mtA[k];
    unsigned short* zz = z + zoffA[k];

    const int tid = threadIdx.x, lane = tid & 63, wv = tid >> 6;
    const int q = lane >> 4, m = lane & 15;
    const int c = bc & 1;
    const int s = wv * 16 + m;
    const float aS = da[c * SS + s], bS = db[c * SS + s];

    f32x4 acc[4] = {};
    const unsigned short* ybase = y + ((size_t)(bc * FF + p + fg * 4) * SS) * NW;
    const float* wrow = W + (size_t)(mt * 16 + m) * NW;

    for (int ks = 0; ks < 4; ++ks) {
        const float* wp = wrow + ks * 32 + q * 8;
        float4 wa = *(const float4*)wp;
        float4 wb = *(const float4*)(wp + 4);
        bf16x8 B;
        B[0] = (short)f2bf(wa.x); B[1] = (short)f2bf(wa.y);
        B[2] = (short)f2bf(wa.z); B[3] = (short)f2bf(wa.w);
        B[4] = (short)f2bf(wb.x); B[5] = (short)f2bf(wb.y);
        B[6] = (short)f2bf(wb.z); B[7] = (short)f2bf(wb.w);
#pragma unroll
        for (int g = 0; g < 4; ++g) {
            const unsigned short* yp = ybase + ((size_t)g * SS + s) * NW + ks * 32 + q * 8;
            bf16x8 ar = *(const bf16x8*)yp;
            bf16x8 af;
#pragma unroll
            for (int j = 0; j < 8; ++j) {
                float f = bf2f((unsigned short)ar[j]);
                f = fmaxf(fmaf(f, aS, bS), 0.f);
                af[j] = (short)f2bf(f);
            }
            acc[g] = __builtin_amdgcn_mfma_f32_16x16x32_bf16(af, B, acc[g], 0, 0, 0);
        }
    }

#pragma unroll
    for (int g = 0; g < 4; ++g) {
        size_t zrow = (size_t)(bc * freqs + fg * 4 + g) * SS;
#pragma unroll
        for (int reg = 0; reg < 4; ++reg) {
            int srow = wv * 16 + q * 4 + reg;
            zz[(zrow + srow) * MT + mt * 16 + m] = f2bf(acc[g][reg]);
        }
    }
}

// ---------------- stage 2 stats from stored z ----------------
__global__ __launch_bounds__(256) void k_zstat(const unsigned short* __restrict__ z,
                                               float* __restrict__ disum,
                                               float* __restrict__ disq)
{
    __shared__ float ssum[4], ssq[4];
    const int tid = threadIdx.x, lane = tid & 63, wv = tid >> 6;
    size_t e0 = (size_t)blockIdx.x * 8192;
    int kb; size_t off, cs;
    if (e0 < 524288)       { kb = 0; off = 0;       cs = 32768;  }
    else if (e0 < 1572864) { kb = 1; off = 524288;  cs = 65536;  }
    else if (e0 < 4718592) { kb = 2; off = 1572864; cs = 196608; }
    else if (e0 < 8912896) { kb = 3; off = 4718592; cs = 262144; }
    else                   { kb = 4; off = 8912896; cs = 524288; }
    int c = (int)(((e0 - off) / cs) & 1);

    float s = 0.f, q = 0.f;
#pragma unroll
    for (int it = 0; it < 4; ++it) {
        const unsigned short* pz = z + e0 + ((size_t)(it * 256 + tid) << 3);
        ushort4 u0 = *(const ushort4*)pz;
        ushort4 u1 = *(const ushort4*)(pz + 4);
        float v;
        v = bf2f(u0.x); s += v; q += v * v;
        v = bf2f(u0.y); s += v; q += v * v;
        v = bf2f(u0.z); s += v; q += v * v;
        v = bf2f(u0.w); s += v; q += v * v;
        v = bf2f(u1.x); s += v; q += v * v;
        v = bf2f(u1.y); s += v; q += v * v;
        v = bf2f(u1.z); s += v; q += v * v;
        v = bf2f(u1.w); s += v; q += v * v;
    }
#pragma unroll
    for (int o = 32; o > 0; o >>= 1) {
        s += __shfl_down(s, o, 64);
        q += __shfl_down(q, o, 64);
    }
    if (lane == 0) { ssum[wv] = s; ssq[wv] = q; }
    __syncthreads();
    if (tid == 0) {
        atomicAdd(&disum[kb * 2 + c], ssum[0] + ssum[1] + ssum[2] + ssum[3]);
        atomicAdd(&disq[kb * 2 + c],  ssq[0] + ssq[1] + ssq[2] + ssq[3]);
    }
}

// ---------------- stage 2b ----------------
__global__ void k_di_ab(const float* __restrict__ disum, const float* __restrict__ disq,
                        const float* __restrict__ g0, const float* __restrict__ g1,
                        const float* __restrict__ g2, const float* __restrict__ g3,
                        const float* __restrict__ g4,
                        const float* __restrict__ b0, const float* __restrict__ b1,
                        const float* __restrict__ b2, const float* __restrict__ b3,
                        const float* __restrict__ b4,
                        float* __restrict__ ab)
{
    int i = threadIdx.x;
    if (i < 10) {
        int kb = i >> 1, c = i & 1;
        const float Nv[5] = {262144.f, 524288.f, 1572864.f, 2097152.f, 4194304.f};
        const float* gp[5] = {g0, g1, g2, g3, g4};
        const float* bp[5] = {b0, b1, b2, b3, b4};
        float mean = disum[i] / Nv[kb];
        float var  = disq[i] / Nv[kb] - mean * mean;
        float a = gp[kb][c] * rsqrtf(var + EPSV);
        ab[i * 2]     = a;
        ab[i * 2 + 1] = bp[kb][c] - mean * a;
    }
}

// ---------------- BN+ReLU epilogue: bf16 z -> fp32 out ----------------
__global__ __launch_bounds__(256) void k_bn_out(
    const unsigned short* __restrict__ z, const float* __restrict__ ab,
    float* __restrict__ out)
{
    int i4 = blockIdx.x * 256 + threadIdx.x;
    if (i4 >= 4325376) return;
    int kb, off4, cs4;
    if (i4 < 131072)       { kb = 0; off4 = 0;       cs4 = 8192;   }
    else if (i4 < 393216)  { kb = 1; off4 = 131072;  cs4 = 16384;  }
    else if (i4 < 1179648) { kb = 2; off4 = 393216;  cs4 = 49152;  }
    else if (i4 < 2228224) { kb = 3; off4 = 1179648; cs4 = 65536;  }
    else                   { kb = 4; off4 = 2228224; cs4 = 131072; }
    int c = ((i4 - off4) / cs4) & 1;
    float a = ab[(kb * 2 + c) * 2], b = ab[(kb * 2 + c) * 2 + 1];
    ushort4 u = *(const ushort4*)(z + (size_t)i4 * 4);
    float4 o;
    o.x = fmaxf(fmaf(bf2f(u.x), a, b), 0.f);
    o.y = fmaxf(fmaf(bf2f(u.y), a, b), 0.f);
    o.z = fmaxf(fmaf(bf2f(u.z), a, b), 0.f);
    o.w = fmaxf(fmaf(bf2f(u.w), a, b), 0.f);
    *(float4*)(out + (size_t)i4 * 4) = o;
}

// ---------------- launch ----------------
extern "C" void kernel_launch(void* const* d_in, const int* in_sizes, int n_in,
                              void* d_out, int out_size, void* d_ws, size_t ws_size,
                              hipStream_t stream)
{
    const float* x      = (const float*)d_in[0];
    const float* imean  = (const float*)d_in[1];
    const float* iscale = (const float*)d_in[2];
    const float* Wdeo   = (const float*)d_in[3];
    const float* gdeo   = (const float*)d_in[4];
    const float* bdeo   = (const float*)d_in[5];
    const float* Wdi[5] = {(const float*)d_in[7],  (const float*)d_in[10],
                           (const float*)d_in[13], (const float*)d_in[16],
                           (const float*)d_in[19]};
    const float* gdi[5] = {(const float*)d_in[8],  (const float*)d_in[11],
                           (const float*)d_in[14], (const float*)d_in[17],
                           (const float*)d_in[20]};
    const float* bdi[5] = {(const float*)d_in[9],  (const float*)d_in[12],
                           (const float*)d_in[15], (const float*)d_in[18],
                           (const float*)d_in[21]};
    float* out = (float*)d_out;
    float* ws  = (float*)d_ws;

    unsigned short* y  = (unsigned short*)(ws + YOFF);
    unsigned short* z  = (unsigned short*)(ws + ZOFF);
    unsigned short* w1 = (unsigned short*)(ws + W1OFF);
    float* st    = ws + STATF;
    float* da    = st + OFF_DA;
    float* db    = st + OFF_DB;
    float* disum = st + OFF_DISUM;
    float* disq  = st + OFF_DISQ;
    float* diab  = st + OFF_DIAB;
    float* statR = st + OFF_STATR;

    k_prep<<<196, 256, 0, stream>>>(Wdeo, w1, st);

    k_deoverlap<<<BB * CC * FF / 2, 256, 0, stream>>>(x, imean, iscale, w1, y, statR);
    k_deo_ab<<<1, 128, 0, stream>>>(statR, gdeo, bdeo, da, db);

    k_deinterp_u<<<4224, 256, 0, stream>>>(y, Wdi[0], Wdi[1], Wdi[2], Wdi[3], Wdi[4],
                                           da, db, z);

    k_zstat<<<2112, 256, 0, stream>>>(z, disum, disq);

    k_di_ab<<<1, 16, 0, stream>>>(disum, disq,
                                  gdi[0], gdi[1], gdi[2], gdi[3], gdi[4],
                                  bdi[0], bdi[1], bdi[2], bdi[3], bdi[4], diab);

    k_bn_out<<<16896, 256, 0, stream>>>(z, diab, out);
}

// Round 7
// 303.804 us; speedup vs baseline: 2.5654x; 1.0266x over previous
//
#include <hip/hip_runtime.h>
#include <cstddef>

// ---------------- problem constants ----------------
#define BB   8
#define CC   2
#define FF   256
#define TT   4160      // ncoefs
#define SS   64        // nb_slices
#define NW   128       // NWIN
#define KW   256       // 2*NWIN
#define EPSV 1e-5f

typedef __attribute__((ext_vector_type(8))) short bf16x8;   // 8 bf16 = 4 VGPRs
typedef __attribute__((ext_vector_type(4))) float f32x4;

// ---------------- ws layout (float offsets) ----------------
// y  : bf16 [4096][64][128] = 33,554,432 ushort = 16,777,216 floats
// z  : bf16 concat buckets  = 17,301,504 ushort =  8,650,752 floats
// w1 : bf16 frag-ordered W_deo = 32,768 ushort  = 16,384 floats
// w2 : bf16 frag-ordered W_di  = 36,864 ushort  = 18,432 floats
// stats: 19,456 floats. Total ≈ 101.9 MB.
#define YOFF    0
#define ZOFF    16777216
#define W1OFF   25427968
#define W2OFF   25444352
#define STATF   25462784
#define OFF_DA     256
#define OFF_DB     384
#define OFF_DIAB   544
#define OFF_STATR  1024    // 64 reps x [sum(128) | sq(128)]  (stage-1)
#define OFF_STATR2 17408   // 64 reps x [sum(16)  | sq(16) ]  (stage-2)
#define NZERO   19456

// manual bf16 conversions (RNE)
__device__ __forceinline__ unsigned short f2bf(float f) {
    unsigned int u = __builtin_bit_cast(unsigned int, f);
    u = (u + 0x7FFFu + ((u >> 16) & 1u)) >> 16;
    return (unsigned short)u;
}
__device__ __forceinline__ float bf2f(unsigned short h) {
    return __builtin_bit_cast(float, (unsigned int)h << 16);
}

// ---------------- prep: zero stats + frag-ordered bf16 W_deo (w1) + W_di (w2) ----------------
// w1: [ks(8)][nt(8)][lane(64)][j(8)]  = Wdeo[(nt*16+(lane&15))*256 + ks*32 + (lane>>4)*8 + j]
// w2 per bucket (Tk=MT/16): [ks(4)][t(Tk)][lane(64)][j(8)]
//                           = Wdi[(t*16+(lane&15))*128 + ks*32 + (lane>>4)*8 + j]
__global__ __launch_bounds__(256) void k_prep(
    const float* __restrict__ Wdeo,
    const float* __restrict__ Wdi0, const float* __restrict__ Wdi1,
    const float* __restrict__ Wdi2, const float* __restrict__ Wdi3,
    const float* __restrict__ Wdi4,
    unsigned short* __restrict__ w1, unsigned short* __restrict__ w2,
    float* __restrict__ statz)
{
    int gid = blockIdx.x * 256 + threadIdx.x;
    if (gid < NZERO) statz[gid] = 0.f;
    int id = gid - NZERO;
    if (id >= 0 && id < 32768) {
        int j = id & 7, lane = (id >> 3) & 63, nt = (id >> 9) & 7, ks = id >> 12;
        int n = nt * 16 + (lane & 15);
        int k = ks * 32 + ((lane >> 4) << 3) + j;
        w1[id] = f2bf(Wdeo[n * KW + k]);
    }
    id -= 32768;
    if (id >= 0 && id < 36864) {
        const float* W; int base, Tk;
        if (id < 2048)       { W = Wdi0; base = 0;     Tk = 1; }
        else if (id < 6144)  { W = Wdi1; base = 2048;  Tk = 2; }
        else if (id < 12288) { W = Wdi2; base = 6144;  Tk = 3; }
        else if (id < 20480) { W = Wdi3; base = 12288; Tk = 4; }
        else                 { W = Wdi4; base = 20480; Tk = 8; }
        int e = id - base;
        int j = e & 7, lane = (e >> 3) & 63, rest = e >> 9;
        int t = rest % Tk, ks = rest / Tk;
        int n = t * 16 + (lane & 15);
        int k = ks * 32 + ((lane >> 4) << 3) + j;
        w2[id] = f2bf(W[n * NW + k]);
    }
}

// ---------------- stage 1: normalize + deoverlap MFMA + stats + coalesced y store ----------------
__global__ __launch_bounds__(256) void k_deoverlap(
    const float* __restrict__ x, const float* __restrict__ imean,
    const float* __restrict__ iscale, const unsigned short* __restrict__ w1,
    unsigned short* __restrict__ y, float* __restrict__ statR)
{
    __shared__ __align__(16) unsigned short shmem[8704];  // xs[2][4288] / ys[64*136]
    __shared__ float psA[4][64], pqA[4][64];
    unsigned short (*xs)[4288] = reinterpret_cast<unsigned short (*)[4288]>(shmem);
    const int tid = threadIdx.x;
    const int r0  = blockIdx.x * 2;
    const int c   = (r0 >> 8) & 1;

    for (int row = 0; row < 2; ++row) {
        const int r = r0 + row;
        const float mval = imean[r & 255], sval = iscale[r & 255];
        const float* xr = x + (size_t)r * TT;
        for (int p2 = tid; p2 < 2144; p2 += 256) {
            int i = p2 * 2;
            int t = i - 64;
            float v0 = 0.f, v1 = 0.f;
            if (t >= 0 && t + 1 < TT) {
                float2 xv = *(const float2*)&xr[t];
                v0 = (xv.x + mval) * sval;
                v1 = (xv.y + mval) * sval;
            }
            int phys = i ^ (((i >> 6) & 7) << 3);
            unsigned int pk = (unsigned int)f2bf(v0) | ((unsigned int)f2bf(v1) << 16);
            *(unsigned int*)&xs[row][phys] = pk;
        }
    }
    __syncthreads();

    const int lane = tid & 63, wv = tid >> 6;
    const int q = lane >> 4, m = lane & 15;

    f32x4 acc[2][4][2] = {};
    for (int ks = 0; ks < 8; ++ks) {
        const int k0 = ks * 32;
        bf16x8 B0 = *(const bf16x8*)(w1 + ((size_t)((ks * 8 + 2 * wv + 0) * 64 + lane) << 3));
        bf16x8 B1 = *(const bf16x8*)(w1 + ((size_t)((ks * 8 + 2 * wv + 1) * 64 + lane) << 3));
#pragma unroll
        for (int row = 0; row < 2; ++row)
#pragma unroll
            for (int st = 0; st < 4; ++st) {
                int idx  = (st * 16 + m) * 64 + k0 + q * 8;
                int phys = idx ^ (((idx >> 6) & 7) << 3);
                bf16x8 A = *(const bf16x8*)&xs[row][phys];
                acc[row][st][0] = __builtin_amdgcn_mfma_f32_16x16x32_bf16(A, B0, acc[row][st][0], 0, 0, 0);
                acc[row][st][1] = __builtin_amdgcn_mfma_f32_16x16x32_bf16(A, B1, acc[row][st][1], 0, 0, 0);
            }
    }

    // y store via LDS transpose (stride 136 keeps banks <=2-way), 16B coalesced global
    for (int row = 0; row < 2; ++row) {
        __syncthreads();   // xs dead / previous ys reads done
#pragma unroll
        for (int st = 0; st < 4; ++st)
#pragma unroll
            for (int t = 0; t < 2; ++t)
#pragma unroll
                for (int reg = 0; reg < 4; ++reg)
                    shmem[(st * 16 + q * 4 + reg) * 136 + (2 * wv + t) * 16 + m] =
                        f2bf(acc[row][st][t][reg]);
        __syncthreads();
#pragma unroll
        for (int it = 0; it < 4; ++it) {
            int e = (it * 256 + tid) * 8;
            int sr = e >> 7, n0 = e & 127;
            *(bf16x8*)(y + (size_t)(r0 + row) * 8192 + e) =
                *(const bf16x8*)(shmem + sr * 136 + n0);
        }
    }

    // per-(c,s) stats -> LDS combine -> replicated atomics
#pragma unroll
    for (int st = 0; st < 4; ++st)
#pragma unroll
        for (int reg = 0; reg < 4; ++reg) {
            float ps = 0.f, pq = 0.f;
#pragma unroll
            for (int row = 0; row < 2; ++row)
#pragma unroll
                for (int t = 0; t < 2; ++t) {
                    float v = acc[row][st][t][reg];
                    ps += v; pq += v * v;
                }
#pragma unroll
            for (int off = 8; off > 0; off >>= 1) {
                ps += __shfl_down(ps, off, 16);
                pq += __shfl_down(pq, off, 16);
            }
            if (m == 0) {
                int s = st * 16 + q * 4 + reg;
                psA[wv][s] = ps;
                pqA[wv][s] = pq;
            }
        }
    __syncthreads();
    if (tid < 128) {
        int s = tid & 63, which = tid >> 6;
        float v = which ? (pqA[0][s] + pqA[1][s] + pqA[2][s] + pqA[3][s])
                        : (psA[0][s] + psA[1][s] + psA[2][s] + psA[3][s]);
        int rep = blockIdx.x & 63;
        atomicAdd(&statR[rep * 256 + which * 128 + c * SS + s], v);
    }
}

// ---------------- stage 1b: fold replicas -> per-(c,s) BN coefficients ----------------
__global__ void k_deo_ab(const float* __restrict__ statR,
                         const float* __restrict__ g, const float* __restrict__ be,
                         float* __restrict__ da, float* __restrict__ db)
{
    int i = threadIdx.x;
    if (i < CC * SS) {
        float sm = 0.f, sq = 0.f;
        for (int rep = 0; rep < 64; ++rep) {
            sm += statR[rep * 256 + i];
            sq += statR[rep * 256 + 128 + i];
        }
        int c = i >> 6;
        const float N = (float)(BB * FF * NW);
        float mean = sm / N;
        float var  = sq / N - mean * mean;
        float a = g[c] * rsqrtf(var + EPSV);
        da[i] = a;
        db[i] = be[c] - mean * a;
    }
}

// ---------------- apply BN+ReLU to y in place (once) ----------------
__global__ __launch_bounds__(256) void k_ybn(
    unsigned short* __restrict__ y,
    const float* __restrict__ da, const float* __restrict__ db)
{
    int i8 = blockIdx.x * 256 + threadIdx.x;     // 4,194,304 threads
    size_t e = (size_t)i8 * 8;
    int s = (int)((e >> 7) & 63);
    int c = (int)((e >> 21) & 1);
    float a = da[c * 64 + s], b = db[c * 64 + s];
    bf16x8 v = *(const bf16x8*)(y + e);
    bf16x8 o;
#pragma unroll
    for (int j = 0; j < 8; ++j) {
        float f = bf2f((unsigned short)v[j]);
        f = fmaxf(fmaf(f, a, b), 0.f);
        o[j] = (short)f2bf(f);
    }
    *(bf16x8*)(y + e) = o;
}

// ---------------- stage 2: pure load+MFMA GEMM + fused replicated stats ----------------
__global__ __launch_bounds__(256) void k_deinterp_u(
    const unsigned short* __restrict__ y, const unsigned short* __restrict__ w2,
    unsigned short* __restrict__ z, float* __restrict__ statR2)
{
    const int cum[6]    = {0, 128, 384, 1152, 2176, 4224};
    const int pA[5]     = {0, 32, 64, 128, 192};
    const int freqsA[5] = {32, 32, 64, 64, 64};
    const int mtA[5]    = {16, 32, 48, 64, 128};
    const int TkA[5]    = {1, 2, 3, 4, 8};
    const int lgFG[5]   = {3, 3, 4, 4, 4};
    const int w2b[5]    = {0, 2048, 6144, 12288, 20480};
    const size_t zoffA[5] = {0, 524288, 1572864, 4718592, 8912896};

    __shared__ float ssum[4], ssq[4];

    int bid = blockIdx.x;
    int k = 0;
    while (k < 4 && bid >= cum[k + 1]) ++k;
    int r = bid - cum[k];
    const int bc = r & 15;  r >>= 4;
    const int fg = r & ((1 << lgFG[k]) - 1);
    const int mt = r >> lgFG[k];

    const int p = pA[k], freqs = freqsA[k], MT = mtA[k], Tk = TkA[k];
    unsigned short* zz = z + zoffA[k];
    const unsigned short* wb = w2 + w2b[k];

    const int tid = threadIdx.x, lane = tid & 63, wv = tid >> 6;
    const int q = lane >> 4, m = lane & 15;
    const int c = bc & 1;
    const int s = wv * 16 + m;

    f32x4 acc[4] = {};
    const unsigned short* ybase = y + ((size_t)(bc * FF + p + fg * 4) * SS) * NW;

#pragma unroll
    for (int ks = 0; ks < 4; ++ks) {
        bf16x8 B = *(const bf16x8*)(wb + ((size_t)((ks * Tk + mt) * 64 + lane) << 3));
#pragma unroll
        for (int g = 0; g < 4; ++g) {
            bf16x8 A = *(const bf16x8*)(ybase + ((size_t)g * SS + s) * NW + ks * 32 + q * 8);
            acc[g] = __builtin_amdgcn_mfma_f32_16x16x32_bf16(A, B, acc[g], 0, 0, 0);
        }
    }

    float ls = 0.f, lq = 0.f;
#pragma unroll
    for (int g = 0; g < 4; ++g) {
        size_t zrow = (size_t)(bc * freqs + fg * 4 + g) * SS;
#pragma unroll
        for (int reg = 0; reg < 4; ++reg) {
            float v = acc[g][reg];
            ls += v; lq += v * v;
            int srow = wv * 16 + q * 4 + reg;
            zz[(zrow + srow) * MT + mt * 16 + m] = f2bf(v);
        }
    }
#pragma unroll
    for (int o = 32; o > 0; o >>= 1) {
        ls += __shfl_down(ls, o, 64);
        lq += __shfl_down(lq, o, 64);
    }
    if (lane == 0) { ssum[wv] = ls; ssq[wv] = lq; }
    __syncthreads();
    if (tid == 0) {
        int rep = blockIdx.x & 63;
        atomicAdd(&statR2[rep * 32 + k * 2 + c],      ssum[0] + ssum[1] + ssum[2] + ssum[3]);
        atomicAdd(&statR2[rep * 32 + 16 + k * 2 + c], ssq[0] + ssq[1] + ssq[2] + ssq[3]);
    }
}

// ---------------- stage 2b: fold replicas -> per-(bucket,c) BN coefficients ----------------
__global__ void k_di_ab(const float* __restrict__ statR2,
                        const float* __restrict__ g0, const float* __restrict__ g1,
                        const float* __restrict__ g2, const float* __restrict__ g3,
                        const float* __restrict__ g4,
                        const float* __restrict__ b0, const float* __restrict__ b1,
                        const float* __restrict__ b2, const float* __restrict__ b3,
                        const float* __restrict__ b4,
                        float* __restrict__ ab)
{
    int i = threadIdx.x;
    if (i < 10) {
        float sm = 0.f, sq = 0.f;
        for (int rep = 0; rep < 64; ++rep) {
            sm += statR2[rep * 32 + i];
            sq += statR2[rep * 32 + 16 + i];
        }
        int kb = i >> 1, c = i & 1;
        const float Nv[5] = {262144.f, 524288.f, 1572864.f, 2097152.f, 4194304.f};
        const float* gp[5] = {g0, g1, g2, g3, g4};
        const float* bp[5] = {b0, b1, b2, b3, b4};
        float mean = sm / Nv[kb];
        float var  = sq / Nv[kb] - mean * mean;
        float a = gp[kb][c] * rsqrtf(var + EPSV);
        ab[i * 2]     = a;
        ab[i * 2 + 1] = bp[kb][c] - mean * a;
    }
}

// ---------------- BN+ReLU epilogue: bf16 z -> fp32 out ----------------
__global__ __launch_bounds__(256) void k_bn_out(
    const unsigned short* __restrict__ z, const float* __restrict__ ab,
    float* __restrict__ out)
{
    int i4 = blockIdx.x * 256 + threadIdx.x;
    if (i4 >= 4325376) return;
    int kb, off4, cs4;
    if (i4 < 131072)       { kb = 0; off4 = 0;       cs4 = 8192;   }
    else if (i4 < 393216)  { kb = 1; off4 = 131072;  cs4 = 16384;  }
    else if (i4 < 1179648) { kb = 2; off4 = 393216;  cs4 = 49152;  }
    else if (i4 < 2228224) { kb = 3; off4 = 1179648; cs4 = 65536;  }
    else                   { kb = 4; off4 = 2228224; cs4 = 131072; }
    int c = ((i4 - off4) / cs4) & 1;
    float a = ab[(kb * 2 + c) * 2], b = ab[(kb * 2 + c) * 2 + 1];
    ushort4 u = *(const ushort4*)(z + (size_t)i4 * 4);
    float4 o;
    o.x = fmaxf(fmaf(bf2f(u.x), a, b), 0.f);
    o.y = fmaxf(fmaf(bf2f(u.y), a, b), 0.f);
    o.z = fmaxf(fmaf(bf2f(u.z), a, b), 0.f);
    o.w = fmaxf(fmaf(bf2f(u.w), a, b), 0.f);
    *(float4*)(out + (size_t)i4 * 4) = o;
}

// ---------------- launch ----------------
extern "C" void kernel_launch(void* const* d_in, const int* in_sizes, int n_in,
                              void* d_out, int out_size, void* d_ws, size_t ws_size,
                              hipStream_t stream)
{
    const float* x      = (const float*)d_in[0];
    const float* imean  = (const float*)d_in[1];
    const float* iscale = (const float*)d_in[2];
    const float* Wdeo   = (const float*)d_in[3];
    const float* gdeo   = (const float*)d_in[4];
    const float* bdeo   = (const float*)d_in[5];
    const float* Wdi[5] = {(const float*)d_in[7],  (const float*)d_in[10],
                           (const float*)d_in[13], (const float*)d_in[16],
                           (const float*)d_in[19]};
    const float* gdi[5] = {(const float*)d_in[8],  (const float*)d_in[11],
                           (const float*)d_in[14], (const float*)d_in[17],
                           (const float*)d_in[20]};
    const float* bdi[5] = {(const float*)d_in[9],  (const float*)d_in[12],
                           (const float*)d_in[15], (const float*)d_in[18],
                           (const float*)d_in[21]};
    float* out = (float*)d_out;
    float* ws  = (float*)d_ws;

    unsigned short* y  = (unsigned short*)(ws + YOFF);
    unsigned short* z  = (unsigned short*)(ws + ZOFF);
    unsigned short* w1 = (unsigned short*)(ws + W1OFF);
    unsigned short* w2 = (unsigned short*)(ws + W2OFF);
    float* st     = ws + STATF;
    float* da     = st + OFF_DA;
    float* db     = st + OFF_DB;
    float* diab   = st + OFF_DIAB;
    float* statR  = st + OFF_STATR;
    float* statR2 = st + OFF_STATR2;

    k_prep<<<348, 256, 0, stream>>>(Wdeo, Wdi[0], Wdi[1], Wdi[2], Wdi[3], Wdi[4],
                                    w1, w2, st);

    k_deoverlap<<<BB * CC * FF / 2, 256, 0, stream>>>(x, imean, iscale, w1, y, statR);
    k_deo_ab<<<1, 128, 0, stream>>>(statR, gdeo, bdeo, da, db);

    k_ybn<<<16384, 256, 0, stream>>>(y, da, db);

    k_deinterp_u<<<4224, 256, 0, stream>>>(y, w2, z, statR2);

    k_di_ab<<<1, 16, 0, stream>>>(statR2,
                                  gdi[0], gdi[1], gdi[2], gdi[3], gdi[4],
                                  bdi[0], bdi[1], bdi[2], bdi[3], bdi[4], diab);

    k_bn_out<<<16896, 256, 0, stream>>>(z, diab, out);
}

// Round 8
// 265.228 us; speedup vs baseline: 2.9385x; 1.1454x over previous
//
#include <hip/hip_runtime.h>
#include <cstddef>

// ---------------- problem constants ----------------
#define BB   8
#define CC   2
#define FF   256
#define TT   4160      // ncoefs
#define SS   64        // nb_slices
#define NW   128       // NWIN
#define KW   256       // 2*NWIN
#define EPSV 1e-5f

typedef __attribute__((ext_vector_type(8))) short bf16x8;   // 8 bf16 = 4 VGPRs
typedef __attribute__((ext_vector_type(4))) float f32x4;

// ---------------- ws layout (float offsets) ----------------
// y  : bf16 [4096][64][128] = 33,554,432 ushort = 16,777,216 floats (64 MiB)
// z  : bf16 concat buckets  = 17,301,504 ushort =  8,650,752 floats
// w1 : bf16 frag-ordered W_deo = 32,768 ushort  = 16,384 floats
// w2 : bf16 frag-ordered W_di  = 36,864 ushort  = 18,432 floats
#define YOFF    0
#define ZOFF    16777216
#define W1OFF   25427968
#define W2OFF   25444352
#define STATF   25462784
#define OFF_DA     256
#define OFF_DB     384
#define OFF_DIAB   544
#define OFF_STATR  1024    // 64 reps x [sum(128) | sq(128)]  (stage-1)
#define OFF_STATR2 17408   // 64 reps x [sum(16)  | sq(16) ]  (stage-2)
#define NZERO   19456

// manual bf16 conversions (RNE)
__device__ __forceinline__ unsigned short f2bf(float f) {
    unsigned int u = __builtin_bit_cast(unsigned int, f);
    u = (u + 0x7FFFu + ((u >> 16) & 1u)) >> 16;
    return (unsigned short)u;
}
__device__ __forceinline__ float bf2f(unsigned short h) {
    return __builtin_bit_cast(float, (unsigned int)h << 16);
}

// ---------------- prep: zero stats + frag-ordered bf16 W_deo (w1) + W_di (w2) ----------------
// w1: [ks(8)][nt(8)][lane(64)][j(8)]  = Wdeo[(nt*16+(lane&15))*256 + ks*32 + (lane>>4)*8 + j]
// w2 per bucket (Tk=MT/16): [ks(4)][t(Tk)][lane(64)][j(8)]
//                           = Wdi[(t*16+(lane&15))*128 + ks*32 + (lane>>4)*8 + j]
__global__ __launch_bounds__(256) void k_prep(
    const float* __restrict__ Wdeo,
    const float* __restrict__ Wdi0, const float* __restrict__ Wdi1,
    const float* __restrict__ Wdi2, const float* __restrict__ Wdi3,
    const float* __restrict__ Wdi4,
    unsigned short* __restrict__ w1, unsigned short* __restrict__ w2,
    float* __restrict__ statz)
{
    int gid = blockIdx.x * 256 + threadIdx.x;
    if (gid < NZERO) statz[gid] = 0.f;
    int id = gid - NZERO;
    if (id >= 0 && id < 32768) {
        int j = id & 7, lane = (id >> 3) & 63, nt = (id >> 9) & 7, ks = id >> 12;
        int n = nt * 16 + (lane & 15);
        int k = ks * 32 + ((lane >> 4) << 3) + j;
        w1[id] = f2bf(Wdeo[n * KW + k]);
    }
    id -= 32768;
    if (id >= 0 && id < 36864) {
        const float* W; int base, Tk;
        if (id < 2048)       { W = Wdi0; base = 0;     Tk = 1; }
        else if (id < 6144)  { W = Wdi1; base = 2048;  Tk = 2; }
        else if (id < 12288) { W = Wdi2; base = 6144;  Tk = 3; }
        else if (id < 20480) { W = Wdi3; base = 12288; Tk = 4; }
        else                 { W = Wdi4; base = 20480; Tk = 8; }
        int e = id - base;
        int j = e & 7, lane = (e >> 3) & 63, rest = e >> 9;
        int t = rest % Tk, ks = rest / Tk;
        int n = t * 16 + (lane & 15);
        int k = ks * 32 + ((lane >> 4) << 3) + j;
        w2[id] = f2bf(W[n * NW + k]);
    }
}

// ---------------- stage 1: normalize + deoverlap MFMA + stats (1 row / block) ----------------
__global__ __launch_bounds__(256) void k_deoverlap(
    const float* __restrict__ x, const float* __restrict__ imean,
    const float* __restrict__ iscale, const unsigned short* __restrict__ w1,
    unsigned short* __restrict__ y, float* __restrict__ statR)
{
    __shared__ __align__(16) unsigned short xs[4288];
    __shared__ float psA[4][64], pqA[4][64];
    const int tid = threadIdx.x;
    const int r   = blockIdx.x;
    const int c   = (r >> 8) & 1;

    {
        const float mval = imean[r & 255], sval = iscale[r & 255];
        const float* xr = x + (size_t)r * TT;
        for (int p2 = tid; p2 < 2144; p2 += 256) {
            int i = p2 * 2;
            int t = i - 64;
            float v0 = 0.f, v1 = 0.f;
            if (t >= 0 && t + 1 < TT) {
                float2 xv = *(const float2*)&xr[t];
                v0 = (xv.x + mval) * sval;
                v1 = (xv.y + mval) * sval;
            }
            int phys = i ^ (((i >> 6) & 7) << 3);
            unsigned int pk = (unsigned int)f2bf(v0) | ((unsigned int)f2bf(v1) << 16);
            *(unsigned int*)&xs[phys] = pk;
        }
    }
    __syncthreads();

    const int lane = tid & 63, wv = tid >> 6;
    const int q = lane >> 4, m = lane & 15;

    f32x4 acc[4][2] = {};   // [stile][ntile]
    for (int ks = 0; ks < 8; ++ks) {
        const int k0 = ks * 32;
        bf16x8 B0 = *(const bf16x8*)(w1 + ((size_t)((ks * 8 + 2 * wv + 0) * 64 + lane) << 3));
        bf16x8 B1 = *(const bf16x8*)(w1 + ((size_t)((ks * 8 + 2 * wv + 1) * 64 + lane) << 3));
#pragma unroll
        for (int st = 0; st < 4; ++st) {
            int idx  = (st * 16 + m) * 64 + k0 + q * 8;
            int phys = idx ^ (((idx >> 6) & 7) << 3);
            bf16x8 A = *(const bf16x8*)&xs[phys];
            acc[st][0] = __builtin_amdgcn_mfma_f32_16x16x32_bf16(A, B0, acc[st][0], 0, 0, 0);
            acc[st][1] = __builtin_amdgcn_mfma_f32_16x16x32_bf16(A, B1, acc[st][1], 0, 0, 0);
        }
    }

    // direct y store (bf16): col n = (2wv+t)*16+m, row s = st*16+q*4+reg
#pragma unroll
    for (int st = 0; st < 4; ++st)
#pragma unroll
        for (int t = 0; t < 2; ++t) {
            int n = (2 * wv + t) * 16 + m;
#pragma unroll
            for (int reg = 0; reg < 4; ++reg) {
                int s = st * 16 + q * 4 + reg;
                y[(size_t)r * 8192 + s * NW + n] = f2bf(acc[st][t][reg]);
            }
        }

    // per-(c,s) stats -> shfl16 -> LDS combine -> replicated atomics
#pragma unroll
    for (int st = 0; st < 4; ++st)
#pragma unroll
        for (int reg = 0; reg < 4; ++reg) {
            float ps = 0.f, pq = 0.f;
#pragma unroll
            for (int t = 0; t < 2; ++t) {
                float v = acc[st][t][reg];
                ps += v; pq += v * v;
            }
#pragma unroll
            for (int off = 8; off > 0; off >>= 1) {
                ps += __shfl_down(ps, off, 16);
                pq += __shfl_down(pq, off, 16);
            }
            if (m == 0) {
                int s = st * 16 + q * 4 + reg;
                psA[wv][s] = ps;
                pqA[wv][s] = pq;
            }
        }
    __syncthreads();
    if (tid < 128) {
        int s = tid & 63, which = tid >> 6;
        float v = which ? (pqA[0][s] + pqA[1][s] + pqA[2][s] + pqA[3][s])
                        : (psA[0][s] + psA[1][s] + psA[2][s] + psA[3][s]);
        int rep = blockIdx.x & 63;
        atomicAdd(&statR[rep * 256 + which * 128 + c * SS + s], v);
    }
}

// ---------------- stage 1b: fold replicas -> per-(c,s) BN coefficients ----------------
__global__ void k_deo_ab(const float* __restrict__ statR,
                         const float* __restrict__ g, const float* __restrict__ be,
                         float* __restrict__ da, float* __restrict__ db)
{
    int i = threadIdx.x;
    if (i < CC * SS) {
        float sm = 0.f, sq = 0.f;
        for (int rep = 0; rep < 64; ++rep) {
            sm += statR[rep * 256 + i];
            sq += statR[rep * 256 + 128 + i];
        }
        int c = i >> 6;
        const float N = (float)(BB * FF * NW);
        float mean = sm / N;
        float var  = sq / N - mean * mean;
        float a = g[c] * rsqrtf(var + EPSV);
        da[i] = a;
        db[i] = be[c] - mean * a;
    }
}

// ---------------- stage 2: fused BN+ReLU + GEMM, ALL m-tiles per block ----------------
// y read exactly once; BN applied once per y element; stats fused (replicated).
template <int Tk, int G>
__global__ __launch_bounds__(256) void k_deinterp(
    const unsigned short* __restrict__ y, const unsigned short* __restrict__ wb,
    const float* __restrict__ da, const float* __restrict__ db,
    unsigned short* __restrict__ zz, float* __restrict__ statR2,
    int p, int freqs, int kidx)
{
    constexpr int MT = Tk * 16;
    __shared__ float ssum[4], ssq[4];
    const int tid = threadIdx.x, lane = tid & 63, wv = tid >> 6;
    const int q = lane >> 4, m = lane & 15;
    const int bc = blockIdx.x & 15;
    const int fg = blockIdx.x >> 4;
    const int c  = bc & 1;
    const int s  = wv * 16 + m;
    const float aS = da[c * SS + s], bS = db[c * SS + s];

    f32x4 acc[G][Tk] = {};
    const unsigned short* ybase = y + ((size_t)(bc * FF + p + fg * G) * SS) * NW;

#pragma unroll
    for (int ks = 0; ks < 4; ++ks) {
        bf16x8 B[Tk];
#pragma unroll
        for (int t = 0; t < Tk; ++t)
            B[t] = *(const bf16x8*)(wb + ((size_t)((ks * Tk + t) * 64 + lane) << 3));
#pragma unroll
        for (int g = 0; g < G; ++g) {
            bf16x8 ar = *(const bf16x8*)(ybase + ((size_t)g * SS + s) * NW + ks * 32 + q * 8);
            bf16x8 af;
#pragma unroll
            for (int j = 0; j < 8; ++j) {
                float f = bf2f((unsigned short)ar[j]);
                f = fmaxf(fmaf(f, aS, bS), 0.f);
                af[j] = (short)f2bf(f);
            }
#pragma unroll
            for (int t = 0; t < Tk; ++t)
                acc[g][t] = __builtin_amdgcn_mfma_f32_16x16x32_bf16(af, B[t], acc[g][t], 0, 0, 0);
        }
    }

    float ls = 0.f, lq = 0.f;
#pragma unroll
    for (int g = 0; g < G; ++g) {
        size_t zrow = (size_t)(bc * freqs + fg * G + g) * SS;
#pragma unroll
        for (int t = 0; t < Tk; ++t)
#pragma unroll
            for (int reg = 0; reg < 4; ++reg) {
                float v = acc[g][t][reg];
                ls += v; lq += v * v;
                int srow = wv * 16 + q * 4 + reg;
                zz[(zrow + srow) * MT + t * 16 + m] = f2bf(v);
            }
    }
#pragma unroll
    for (int o = 32; o > 0; o >>= 1) {
        ls += __shfl_down(ls, o, 64);
        lq += __shfl_down(lq, o, 64);
    }
    if (lane == 0) { ssum[wv] = ls; ssq[wv] = lq; }
    __syncthreads();
    if (tid == 0) {
        int rep = blockIdx.x & 63;
        atomicAdd(&statR2[rep * 32 + kidx * 2 + c],      ssum[0] + ssum[1] + ssum[2] + ssum[3]);
        atomicAdd(&statR2[rep * 32 + 16 + kidx * 2 + c], ssq[0] + ssq[1] + ssq[2] + ssq[3]);
    }
}

// ---------------- stage 2b: fold replicas -> per-(bucket,c) BN coefficients ----------------
__global__ void k_di_ab(const float* __restrict__ statR2,
                        const float* __restrict__ g0, const float* __restrict__ g1,
                        const float* __restrict__ g2, const float* __restrict__ g3,
                        const float* __restrict__ g4,
                        const float* __restrict__ b0, const float* __restrict__ b1,
                        const float* __restrict__ b2, const float* __restrict__ b3,
                        const float* __restrict__ b4,
                        float* __restrict__ ab)
{
    int i = threadIdx.x;
    if (i < 10) {
        float sm = 0.f, sq = 0.f;
        for (int rep = 0; rep < 64; ++rep) {
            sm += statR2[rep * 32 + i];
            sq += statR2[rep * 32 + 16 + i];
        }
        int kb = i >> 1, c = i & 1;
        const float Nv[5] = {262144.f, 524288.f, 1572864.f, 2097152.f, 4194304.f};
        const float* gp[5] = {g0, g1, g2, g3, g4};
        const float* bp[5] = {b0, b1, b2, b3, b4};
        float mean = sm / Nv[kb];
        float var  = sq / Nv[kb] - mean * mean;
        float a = gp[kb][c] * rsqrtf(var + EPSV);
        ab[i * 2]     = a;
        ab[i * 2 + 1] = bp[kb][c] - mean * a;
    }
}

// ---------------- BN+ReLU epilogue: bf16 z -> fp32 out ----------------
__global__ __launch_bounds__(256) void k_bn_out(
    const unsigned short* __restrict__ z, const float* __restrict__ ab,
    float* __restrict__ out)
{
    int i4 = blockIdx.x * 256 + threadIdx.x;
    if (i4 >= 4325376) return;
    int kb, off4, cs4;
    if (i4 < 131072)       { kb = 0; off4 = 0;       cs4 = 8192;   }
    else if (i4 < 393216)  { kb = 1; off4 = 131072;  cs4 = 16384;  }
    else if (i4 < 1179648) { kb = 2; off4 = 393216;  cs4 = 49152;  }
    else if (i4 < 2228224) { kb = 3; off4 = 1179648; cs4 = 65536;  }
    else                   { kb = 4; off4 = 2228224; cs4 = 131072; }
    int c = ((i4 - off4) / cs4) & 1;
    float a = ab[(kb * 2 + c) * 2], b = ab[(kb * 2 + c) * 2 + 1];
    ushort4 u = *(const ushort4*)(z + (size_t)i4 * 4);
    float4 o;
    o.x = fmaxf(fmaf(bf2f(u.x), a, b), 0.f);
    o.y = fmaxf(fmaf(bf2f(u.y), a, b), 0.f);
    o.z = fmaxf(fmaf(bf2f(u.z), a, b), 0.f);
    o.w = fmaxf(fmaf(bf2f(u.w), a, b), 0.f);
    *(float4*)(out + (size_t)i4 * 4) = o;
}

// ---------------- launch ----------------
extern "C" void kernel_launch(void* const* d_in, const int* in_sizes, int n_in,
                              void* d_out, int out_size, void* d_ws, size_t ws_size,
                              hipStream_t stream)
{
    const float* x      = (const float*)d_in[0];
    const float* imean  = (const float*)d_in[1];
    const float* iscale = (const float*)d_in[2];
    const float* Wdeo   = (const float*)d_in[3];
    const float* gdeo   = (const float*)d_in[4];
    const float* bdeo   = (const float*)d_in[5];
    const float* Wdi[5] = {(const float*)d_in[7],  (const float*)d_in[10],
                           (const float*)d_in[13], (const float*)d_in[16],
                           (const float*)d_in[19]};
    const float* gdi[5] = {(const float*)d_in[8],  (const float*)d_in[11],
                           (const float*)d_in[14], (const float*)d_in[17],
                           (const float*)d_in[20]};
    const float* bdi[5] = {(const float*)d_in[9],  (const float*)d_in[12],
                           (const float*)d_in[15], (const float*)d_in[18],
                           (const float*)d_in[21]};
    float* out = (float*)d_out;
    float* ws  = (float*)d_ws;

    unsigned short* y  = (unsigned short*)(ws + YOFF);
    unsigned short* z  = (unsigned short*)(ws + ZOFF);
    unsigned short* w1 = (unsigned short*)(ws + W1OFF);
    unsigned short* w2 = (unsigned short*)(ws + W2OFF);
    float* st     = ws + STATF;
    float* da     = st + OFF_DA;
    float* db     = st + OFF_DB;
    float* diab   = st + OFF_DIAB;
    float* statR  = st + OFF_STATR;
    float* statR2 = st + OFF_STATR2;

    k_prep<<<348, 256, 0, stream>>>(Wdeo, Wdi[0], Wdi[1], Wdi[2], Wdi[3], Wdi[4],
                                    w1, w2, st);

    k_deoverlap<<<BB * CC * FF, 256, 0, stream>>>(x, imean, iscale, w1, y, statR);
    k_deo_ab<<<1, 128, 0, stream>>>(statR, gdeo, bdeo, da, db);

    k_deinterp<1, 4><<<16 * 8,  256, 0, stream>>>(y, w2 + 0,     da, db, z + 0,       statR2,   0, 32, 0);
    k_deinterp<2, 4><<<16 * 8,  256, 0, stream>>>(y, w2 + 2048,  da, db, z + 524288,  statR2,  32, 32, 1);
    k_deinterp<3, 4><<<16 * 16, 256, 0, stream>>>(y, w2 + 6144,  da, db, z + 1572864, statR2,  64, 64, 2);
    k_deinterp<4, 4><<<16 * 16, 256, 0, stream>>>(y, w2 + 12288, da, db, z + 4718592, statR2, 128, 64, 3);
    k_deinterp<8, 2><<<16 * 32, 256, 0, stream>>>(y, w2 + 20480, da, db, z + 8912896, statR2, 192, 64, 4);

    k_di_ab<<<1, 16, 0, stream>>>(statR2,
                                  gdi[0], gdi[1], gdi[2], gdi[3], gdi[4],
                                  bdi[0], bdi[1], bdi[2], bdi[3], bdi[4], diab);

    k_bn_out<<<16896, 256, 0, stream>>>(z, diab, out);
}